// Round 4
// baseline (474.437 us; speedup 1.0000x reference)
//
#include <hip/hip_runtime.h>

// CostVolume: out[b,h,w,i0*9+j0] = mean_c( prv[b,h,w,c] * nxt[b,h+i0-4,w+j0-4,c] )
// B=16, H=W=128, C=192, r=4, d=9, 81 offsets. fp32 in/out, bf16 MFMA internally.
//
// v4: reg-staged bf16 LDS double-buffer at 4 blocks/CU.
//  - v3 post-mortem: gll forced conservative vmcnt(0) before each chunk's ds_reads
//    (compiler can't prove LDS disjointness) + 64KiB LDS halved occupancy + the
//    n/12 Gram mapping made a 3-way bank conflict no XOR can fix.
//  - Fix 1 (mapping): Gram columns = full 16x16 halo, set s = halo row, lane m =
//    halo col. Each wave accumulates only its 12 useful rows (acc[12], roff[ls]
//    absorbs wr; all reg indices static). Stride-80 pixel slots -> exact 2-way
//    (free) ds_read_b128 pattern.
//  - Fix 2 (pipeline): T14 split. Chunk c(kk+1) global loads (8 dwordx4/thread,
//    one halo pixel each) issued BEFORE compute kk; converted (v_cvt_pk_bf16_f32)
//    and ds_written AFTER compute; raw s_barrier preceded by lgkmcnt(0) only, so
//    c(kk+2) loads stay in flight across it. A-fragments prefetched identically.
//    No vmcnt ties ds_reads to globals -> no serialization.
//  - LDS 2x20480 staging, reused for epilogue G (39168B) -> 40960 total = 4/CU.
//  - XCD swizzle kept (v3: FETCH 298->212MB).

typedef __attribute__((ext_vector_type(8))) short short8;
typedef __attribute__((ext_vector_type(4))) float float4v;
typedef __attribute__((ext_vector_type(4))) unsigned int uint4v;

#define HH 128
#define WW 128
#define CC 192
#define PSTR 80                    // LDS bytes per halo-pixel chunk (64B bf16 + 16 pad)
#define BUFB (256 * PSTR)          // 20480 per staging buffer
#define GROWP 17
#define GWAVE (144 * GROWP)        // 2448 floats per wave's G region

static __device__ __forceinline__ unsigned int pk2(float lo, float hi) {
    unsigned int r;
    asm("v_cvt_pk_bf16_f32 %0, %1, %2" : "=v"(r) : "v"(lo), "v"(hi));
    return r;
}

static __device__ __forceinline__ short8 cvt8r(float4v f0, float4v f1) {
    union { unsigned int u[4]; short8 s; } r;
    r.u[0] = pk2(f0[0], f0[1]);
    r.u[1] = pk2(f0[2], f0[3]);
    r.u[2] = pk2(f1[0], f1[1]);
    r.u[3] = pk2(f1[2], f1[3]);
    return r.s;
}

// convert 32 staged fp32 -> 64B bf16 pixel chunk, masked, 4x ds_write_b128
static __device__ __forceinline__ void cvt_store(unsigned char* dst,
                                                 const float4v sv[8],
                                                 unsigned wmask) {
#pragma unroll
    for (int g = 0; g < 4; ++g) {
        uint4v w;
        w.x = pk2(sv[2*g][0],   sv[2*g][1])   & wmask;
        w.y = pk2(sv[2*g][2],   sv[2*g][3])   & wmask;
        w.z = pk2(sv[2*g+1][0], sv[2*g+1][1]) & wmask;
        w.w = pk2(sv[2*g+1][2], sv[2*g+1][3]) & wmask;
        *reinterpret_cast<uint4v*>(dst + g * 16) = w;
    }
}

__global__ __launch_bounds__(256, 4) void costvol_kernel(
    const float* __restrict__ prv,
    const float* __restrict__ nxt,
    float* __restrict__ out)
{
    const int tid  = threadIdx.x;        // 0..255
    const int lane = tid & 63;
    const int wv   = tid >> 6;
    const int m    = lane & 15;
    const int q    = lane >> 4;
    const int wr   = wv >> 1, wc = wv & 1;

    // XCD-aware swizzle: 4096 blocks, 8 XCDs, 512 contiguous (=2 images) each
    int bid = blockIdx.x + (blockIdx.y << 4) + (blockIdx.z << 8);
    bid = (bid & 7) * 512 + (bid >> 3);
    const int wt = bid & 15, ht = (bid >> 4) & 15, b = bid >> 8;
    const int h0 = ht * 8, w0 = wt * 8;

    const float* nxt_b = nxt + (size_t)b * HH * WW * CC;
    const float* prv_b = prv + (size_t)b * HH * WW * CC;

    __shared__ alignas(16) unsigned char smem[2 * BUFB];

    // ---- staging: thread owns halo pixel P = tid of the 16x16 halo ----
    const int hr = tid >> 4, hcp = tid & 15;
    const int gh = h0 - 4 + hr, gw_ = w0 - 4 + hcp;
    const bool okp = (gh >= 0) && (gh < HH) && (gw_ >= 0) && (gw_ < WW);
    const unsigned wmask = okp ? 0xFFFFFFFFu : 0u;
    const int ghc = gh  < 0 ? 0 : (gh  > HH - 1 ? HH - 1 : gh);
    const int gwc = gw_ < 0 ? 0 : (gw_ > WW - 1 ? WW - 1 : gw_);
    const float* gpix = nxt_b + ((size_t)ghc * WW + gwc) * CC;
    const int wbase = tid * PSTR;

    // ---- B-fragment read offsets: set ls -> halo row wr*4+ls, lane m = halo col.
    // bank slot = (5m+q)&7 -> exact 2-way (free).
    int roff[12];
#pragma unroll
    for (int ls = 0; ls < 12; ++ls)
        roff[ls] = ((wr * 4 + ls) * 16 + m) * PSTR + q * 16;

    // ---- A operand: lane (q,m) holds prv pixel m of its wave's 4x4 quadrant ----
    const float* pbase =
        prv_b + ((size_t)(h0 + wr * 4 + (m >> 2)) * WW + (w0 + wc * 4 + (m & 3))) * CC + q * 8;

    float4v ar0, ar1;     // raw A staging (chunk kk+1)
    float4v sv[8];        // raw nxt staging (chunk kk+1), one pixel-chunk

    // ---- prologue: chunk 0 ----
    ar0 = *reinterpret_cast<const float4v*>(pbase + 0);
    ar1 = *reinterpret_cast<const float4v*>(pbase + 4);
#pragma unroll
    for (int i = 0; i < 8; ++i)
        sv[i] = *reinterpret_cast<const float4v*>(gpix + i * 4);
    short8 a_cur = cvt8r(ar0, ar1);
    cvt_store(smem + wbase, sv, wmask);
    // issue chunk 1 (stays in flight across the barrier)
    ar0 = *reinterpret_cast<const float4v*>(pbase + 32);
    ar1 = *reinterpret_cast<const float4v*>(pbase + 36);
#pragma unroll
    for (int i = 0; i < 8; ++i)
        sv[i] = *reinterpret_cast<const float4v*>(gpix + 32 + i * 4);
    asm volatile("s_waitcnt lgkmcnt(0)" ::: "memory");
    __builtin_amdgcn_sched_barrier(0);
    __builtin_amdgcn_s_barrier();
    __builtin_amdgcn_sched_barrier(0);

    float4v acc[12];
#pragma unroll
    for (int ls = 0; ls < 12; ++ls) acc[ls] = (float4v){0.f, 0.f, 0.f, 0.f};

    // ---- main loop: 6 chunks of 32 channels, double-buffered bf16 LDS ----
#pragma unroll
    for (int kk = 0; kk < 6; ++kk) {
        const int rb = (kk & 1) * BUFB;
#pragma unroll
        for (int ls = 0; ls < 12; ++ls) {
            short8 bf = *reinterpret_cast<const short8*>(smem + rb + roff[ls]);
            acc[ls] = __builtin_amdgcn_mfma_f32_16x16x32_bf16(a_cur, bf, acc[ls], 0, 0, 0);
        }
        if (kk < 5) {
            short8 a_nxt = cvt8r(ar0, ar1);           // waits A(kk+1) (counted)
            cvt_store(smem + ((kk + 1) & 1) * BUFB + wbase, sv, wmask);  // c(kk+1)
            if (kk < 4) {                              // issue c(kk+2), A(kk+2)
                ar0 = *reinterpret_cast<const float4v*>(pbase + (kk + 2) * 32);
                ar1 = *reinterpret_cast<const float4v*>(pbase + (kk + 2) * 32 + 4);
#pragma unroll
                for (int i = 0; i < 8; ++i)
                    sv[i] = *reinterpret_cast<const float4v*>(gpix + (kk + 2) * 32 + i * 4);
            }
            asm volatile("s_waitcnt lgkmcnt(0)" ::: "memory");
            __builtin_amdgcn_sched_barrier(0);
            __builtin_amdgcn_s_barrier();              // loads stay in flight
            __builtin_amdgcn_sched_barrier(0);
            a_cur = a_nxt;
        }
    }

    // ---- epilogue: G through LDS (reuses staging), coalesced stores ----
    __syncthreads();                                   // all waves done reading bufs
    float* Gf = reinterpret_cast<float*>(smem);
    const int gbase = wv * GWAVE;
    const int lc = m - wc * 4;                         // local halo col 0..11 (else idle)
    if (lc >= 0 && lc < 12) {
#pragma unroll
        for (int ls = 0; ls < 12; ++ls) {
            int col = ls * 12 + lc;
#pragma unroll
            for (int r = 0; r < 4; ++r)
                Gf[gbase + col * GROWP + q * 4 + r] = acc[ls][r];
        }
    }
    __syncthreads();

    const float scale = 1.0f / 192.0f;
    // 8x8 px * 81 offsets = 5184 floats, flat-indexed; rows of 648 floats contiguous.
#pragma unroll
    for (int t = 0; t < 21; ++t) {
        int f = t * 256 + tid;
        if (f < 5184) {
            int p   = f / 81;            // tile pixel 0..63
            int k   = f - p * 81;        // offset 0..80
            int i0  = k / 9, j0 = k - i0 * 9;
            int pr8 = p >> 3, pc8 = p & 7;
            int gw  = ((pr8 >> 2) << 1) | (pc8 >> 2);        // owning wave
            int pi  = ((pr8 & 3) << 2) | (pc8 & 3);          // pixel within quadrant
            int col = ((pr8 & 3) + i0) * 12 + ((pc8 & 3) + j0);
            float v = Gf[gw * GWAVE + col * GROWP + pi] * scale;
            out[((size_t)(b * HH + (h0 + pr8)) * WW + (w0 + pc8)) * 81 + k] = v;
        }
    }
}

extern "C" void kernel_launch(void* const* d_in, const int* in_sizes, int n_in,
                              void* d_out, int out_size, void* d_ws, size_t ws_size,
                              hipStream_t stream) {
    const float* prv = (const float*)d_in[0];
    const float* nxt = (const float*)d_in[1];
    float* out = (float*)d_out;
    dim3 grid(WW / 8, HH / 8, 16);
    dim3 block(256);
    hipLaunchKernelGGL(costvol_kernel, grid, block, 0, stream, prv, nxt, out);
}